// Round 10
// baseline (291.922 us; speedup 1.0000x reference)
//
#include <hip/hip_runtime.h>
#include <hip/hip_bf16.h>
#include <cstddef>
#include <cstdint>

// Problem constants
#define N0 100000
#define N1 25000
#define N2 6250
#define N3 1600
#define DEG 16
#define D_IN 512
#define D_H 256

#define E0 (N1*DEG)   // 400000
#define E1 (N2*DEG)   // 100000
#define E2 (N3*DEG)   // 25600

typedef _Float16 half_t;
typedef __attribute__((ext_vector_type(8))) _Float16 f16x8;
typedef __attribute__((ext_vector_type(4))) float f32x4;

#define XLB 12500                       // xconv half-table blocks: N0*256/8/256
#define WB 2304                         // wconv blocks: 589824/256
#define HB (((E0+E1+E2) + 255) / 256)   // hist/fill blocks: 2054

// ---------------------------------------------------------------------------
// async global -> LDS, 16 bytes per lane (linear LDS dest, per-lane global src)
// ---------------------------------------------------------------------------
__device__ __forceinline__ void gl_lds16(const void* g, void* l)
{
    __builtin_amdgcn_global_load_lds(
        (const __attribute__((address_space(1))) void*)g,
        (__attribute__((address_space(3))) void*)l,
        16, 0, 0);
}

// ---------------------------------------------------------------------------
// xconv half-row: thread t converts 8 floats of columns [COFF, COFF+256) of
// row t>>5 to fp16.
// ---------------------------------------------------------------------------
template<int COFF>
__device__ __forceinline__ void xconv_half(const float* __restrict__ x,
                                           half_t* __restrict__ xh, int t)
{
    const int r = t >> 5;
    const int c = COFF + ((t & 31) << 3);
    const float4* p = reinterpret_cast<const float4*>(x + (size_t)r * D_IN + c);
    const float4 a = p[0], b = p[1];
    f16x8 o;
    o[0] = (half_t)a.x; o[1] = (half_t)a.y; o[2] = (half_t)a.z; o[3] = (half_t)a.w;
    o[4] = (half_t)b.x; o[5] = (half_t)b.y; o[6] = (half_t)b.z; o[7] = (half_t)b.w;
    *reinterpret_cast<f16x8*>(xh + (size_t)r * D_IN + c) = o;
}

// ---------------------------------------------------------------------------
// Gather-mean of one column-half: TPN=32 lanes per node, cols [COFF,COFF+256).
// ---------------------------------------------------------------------------
template<int COFF>
__device__ __forceinline__ void gather_half_node(
    const half_t* __restrict__ feat, const int* __restrict__ esrc,
    const int* __restrict__ ptr, half_t* __restrict__ mean,
    int node, int gl, int n)
{
    constexpr int TPN = 32;
    if (node >= n) return;
    const int beg = ptr[node], end = ptr[node + 1];
    float acc[8] = {};
    for (int base = beg; base < end; base += TPN) {
        const int rem = end - base;
        const int cnt = (rem < TPN) ? rem : TPN;
        const int myidx = (gl < cnt) ? esrc[base + gl] : 0;
        int j = 0;
        for (; j + 7 < cnt; j += 8) {
            int a[8];
            #pragma unroll
            for (int u = 0; u < 8; ++u) a[u] = __shfl(myidx, j + u, TPN);
            f16x8 v[8];
            #pragma unroll
            for (int u = 0; u < 8; ++u)
                v[u] = *reinterpret_cast<const f16x8*>(feat + (size_t)a[u] * D_IN + COFF + (size_t)gl * 8);
            #pragma unroll
            for (int u = 0; u < 8; ++u)
                #pragma unroll
                for (int i = 0; i < 8; ++i) acc[i] += (float)v[u][i];
        }
        for (; j < cnt; ++j) {
            const int a0 = __shfl(myidx, j, TPN);
            const f16x8 v0 = *reinterpret_cast<const f16x8*>(feat + (size_t)a0 * D_IN + COFF + (size_t)gl * 8);
            #pragma unroll
            for (int i = 0; i < 8; ++i) acc[i] += (float)v0[i];
        }
    }
    const float r = 1.0f / fmaxf((float)(end - beg), 1.0f);
    f16x8 o;
    #pragma unroll
    for (int i = 0; i < 8; ++i) o[i] = (half_t)(acc[i] * r);
    *reinterpret_cast<f16x8*>(mean + (size_t)node * D_IN + COFF + (size_t)gl * 8) = o;
}

// ---------------------------------------------------------------------------
// K1: {xconv lo-half | wconv | hist3}
// ---------------------------------------------------------------------------
__global__ __launch_bounds__(256)
void front1_kernel(const float* __restrict__ x, half_t* __restrict__ xh,
                   const float* s0, const float* s1, const float* s2, const float* s3,
                   const float* s4, const float* s5, const float* s6,
                   half_t* t0, half_t* t1, half_t* t2, half_t* t3,
                   half_t* t4, half_t* t5, half_t* t6,
                   const int* __restrict__ d0, const int* __restrict__ d1,
                   const int* __restrict__ d2,
                   int* __restrict__ c0, int* __restrict__ c1, int* __restrict__ c2)
{
    const int bid = blockIdx.x;
    if (bid < XLB) {
        xconv_half<0>(x, xh, bid * 256 + threadIdx.x);
    } else if (bid < XLB + WB) {
        const int id = (bid - XLB) * 256 + threadIdx.x;
        const float* src; half_t* dst; int kb; int e;
        if (id < 131072)      { src = s0; dst = t0; kb = 9; e = id; }
        else if (id < 262144) { src = s1; dst = t1; kb = 9; e = id - 131072; }
        else if (id < 327680) { src = s2; dst = t2; kb = 8; e = id - 262144; }
        else if (id < 393216) { src = s3; dst = t3; kb = 8; e = id - 327680; }
        else if (id < 458752) { src = s4; dst = t4; kb = 8; e = id - 393216; }
        else if (id < 524288) { src = s5; dst = t5; kb = 8; e = id - 458752; }
        else if (id < 589824) { src = s6; dst = t6; kb = 8; e = id - 524288; }
        else return;
        const int K = 1 << kb;
        const int nn = e >> kb, k = e & (K - 1);
        dst[((size_t)nn << kb) + k] = (half_t)src[(size_t)k * 256 + nn];
    } else {
        const int i = (bid - XLB - WB) * 256 + threadIdx.x;
        if (i < E0)                atomicAdd(&c0[d0[i]], 1);
        else if (i < E0 + E1)      atomicAdd(&c1[d1[i - E0]], 1);
        else if (i < E0 + E1 + E2) atomicAdd(&c2[d2[i - E0 - E1]], 1);
    }
}

// ---------------------------------------------------------------------------
// K4: {xconv hi-half || gather lo-half}, block-interleaved (bid%5==4 -> gather)
// so both kinds are co-resident on the CUs from the start.
// ---------------------------------------------------------------------------
__global__ __launch_bounds__(256)
void front2_kernel(const float* __restrict__ x, half_t* __restrict__ xh,
                   const int* __restrict__ esrc, const int* __restrict__ ptr,
                   half_t* __restrict__ mean)
{
    const int bid = blockIdx.x;
    if ((bid % 5) == 4) {
        const int g = bid / 5;                   // 0..3124
        gather_half_node<0>(xh, esrc, ptr, mean,
                            g * 8 + (int)(threadIdx.x >> 5),
                            (int)(threadIdx.x & 31), N1);
    } else {
        const int cidx = bid - bid / 5;          // 0..12499
        xconv_half<256>(x, xh, cidx * 256 + threadIdx.x);
    }
}

// K5: gather hi-half
__global__ __launch_bounds__(256)
void gather_hi_kernel(const half_t* __restrict__ xh,
                      const int* __restrict__ esrc, const int* __restrict__ ptr,
                      half_t* __restrict__ mean)
{
    gather_half_node<256>(xh, esrc, ptr, mean,
                          blockIdx.x * 8 + (int)(threadIdx.x >> 5),
                          (int)(threadIdx.x & 31), N1);
}

// ---------------------------------------------------------------------------
// fill3: scatter src values into dst-ordered buckets
// ---------------------------------------------------------------------------
__global__ void fill3_kernel(const int* __restrict__ s0, const int* __restrict__ d0,
                             const int* __restrict__ s1, const int* __restrict__ d1,
                             const int* __restrict__ s2, const int* __restrict__ d2,
                             int* __restrict__ u0, int* __restrict__ u1, int* __restrict__ u2,
                             int* __restrict__ e0, int* __restrict__ e1, int* __restrict__ e2)
{
    const int i = blockIdx.x * 256 + threadIdx.x;
    if (i < E0) {
        const int p = atomicAdd(&u0[d0[i]], 1); e0[p] = s0[i];
    } else if (i < E0 + E1) {
        const int j = i - E0;
        const int p = atomicAdd(&u1[d1[j]], 1); e1[p] = s1[j];
    } else if (i < E0 + E1 + E2) {
        const int j = i - E0 - E1;
        const int p = atomicAdd(&u2[d2[j]], 1); e2[p] = s2[j];
    }
}

// 3-phase block scan; block b handles layer b.
__global__ __launch_bounds__(1024)
void scan3_kernel(const int* __restrict__ c0, int* __restrict__ p0, int* __restrict__ u0,
                  const int* __restrict__ c1, int* __restrict__ p1, int* __restrict__ u1,
                  const int* __restrict__ c2, int* __restrict__ p2, int* __restrict__ u2)
{
    const int b = blockIdx.x;
    const int* cnt = (b == 0) ? c0 : (b == 1) ? c1 : c2;
    int* ptr = (b == 0) ? p0 : (b == 1) ? p1 : p2;
    int* cur = (b == 0) ? u0 : (b == 1) ? u1 : u2;
    const int n = (b == 0) ? N1 : (b == 1) ? N2 : N3;

    const int t = threadIdx.x;
    const int chunk = (n + 1023) >> 10;
    const int beg = t * chunk;
    const int end = min(n, beg + chunk);

    int sum = 0;
    for (int i = beg; i < end; ++i) sum += cnt[i];

    const int lane = t & 63, wid = t >> 6;
    int inc = sum;
    #pragma unroll
    for (int d = 1; d < 64; d <<= 1) {
        int u = __shfl_up(inc, d, 64);
        if (lane >= d) inc += u;
    }
    __shared__ int wtot[16];
    __shared__ int total_s;
    if (lane == 63) wtot[wid] = inc;
    __syncthreads();
    if (wid == 0) {
        int w = (lane < 16) ? wtot[lane] : 0;
        int ws = w;
        #pragma unroll
        for (int d = 1; d < 16; d <<= 1) {
            int u = __shfl_up(ws, d, 64);
            if (lane >= d) ws += u;
        }
        if (lane < 16) wtot[lane] = ws - w;   // exclusive wave offset
        if (lane == 15) total_s = ws;         // block total
    }
    __syncthreads();
    int run = (inc - sum) + wtot[wid];
    for (int i = beg; i < end; ++i) {
        ptr[i] = run; cur[i] = run;
        run += cnt[i];
    }
    if (t == 0) ptr[n] = total_s;
}

// ---------------------------------------------------------------------------
// CSR gather-mean full-row (layers 1,2): TPN = K/8 lanes per node.
// ---------------------------------------------------------------------------
template<int K>
__global__ __launch_bounds__(256)
void csr_mean_f16(const half_t* __restrict__ h, const int* __restrict__ esrc,
                  const int* __restrict__ ptr, half_t* __restrict__ mean, int n)
{
    constexpr int TPN = K / 8;
    constexpr int NPB = 256 / TPN;
    const int node = blockIdx.x * NPB + threadIdx.x / TPN;
    const int lane = threadIdx.x % TPN;
    if (node >= n) return;
    const int beg = ptr[node], end = ptr[node + 1];
    float acc[8] = {};
    for (int base = beg; base < end; base += TPN) {
        const int rem = end - base;
        const int cnt = (rem < TPN) ? rem : TPN;
        const int myidx = (lane < cnt) ? esrc[base + lane] : 0;
        int j = 0;
        for (; j + 7 < cnt; j += 8) {
            int a[8];
            #pragma unroll
            for (int u = 0; u < 8; ++u) a[u] = __shfl(myidx, j + u, TPN);
            f16x8 v[8];
            #pragma unroll
            for (int u = 0; u < 8; ++u)
                v[u] = *reinterpret_cast<const f16x8*>(h + (size_t)a[u] * K + (size_t)lane * 8);
            #pragma unroll
            for (int u = 0; u < 8; ++u)
                #pragma unroll
                for (int i = 0; i < 8; ++i) acc[i] += (float)v[u][i];
        }
        for (; j < cnt; ++j) {
            const int a0 = __shfl(myidx, j, TPN);
            const f16x8 v0 = *reinterpret_cast<const f16x8*>(h + (size_t)a0 * K + (size_t)lane * 8);
            #pragma unroll
            for (int i = 0; i < 8; ++i) acc[i] += (float)v0[i];
        }
    }
    const float r = 1.0f / fmaxf((float)(end - beg), 1.0f);
    f16x8 o;
    #pragma unroll
    for (int i = 0; i < 8; ++i) o[i] = (half_t)(acc[i] * r);
    *reinterpret_cast<f16x8*>(mean + (size_t)node * K + (size_t)lane * 8) = o;
}

// ---------------------------------------------------------------------------
// MFMA GEMM (round-9 proven): C[M x 256] = A @ WsT^T (+ Mean @ WnT^T) + bias.
// Tile 64x256, BK=64; global_load_lds w16 into XOR-swizzled linear LDS.
// ---------------------------------------------------------------------------
#define GBM 64
#define GBK 64

template<bool HAS_MEAN, bool RELU, bool OUT_F16>
__global__ __launch_bounds__(512)
void mfma_gemm(const half_t* __restrict__ A,
               const half_t* __restrict__ Mn,
               const half_t* __restrict__ WsT,
               const half_t* __restrict__ WnT,
               const float* __restrict__ bias,
               void* __restrict__ Cout,
               int M, int K)
{
    __shared__ half_t sA[GBM * GBK];    // 8 KB
    __shared__ half_t sB[256 * GBK];    // 32 KB

    const int tid  = threadIdx.x;
    const int wid  = tid >> 6;          // 0..7
    const int lane = tid & 63;
    const int bm   = blockIdx.x * GBM;

    const int lrow = lane & 15;
    const int kg16 = (lane >> 4) << 4;  // k-slice byte offset: 0,16,32,48

    f32x4 acc[4][2] = {};

    const int npass = HAS_MEAN ? 2 : 1;
    for (int pass = 0; pass < npass; ++pass) {
        const half_t* __restrict__ Ap = (HAS_MEAN && pass) ? Mn : A;
        const half_t* __restrict__ Wp = (HAS_MEAN && pass) ? WnT : WsT;

        for (int k0 = 0; k0 < K; k0 += GBK) {
            {
                const int Lb  = wid << 10;
                const int L   = Lb + (lane << 4);
                const int row = L >> 7;
                const int c   = (L & 127) ^ ((row & 7) << 4);
                gl_lds16(Ap + (size_t)(bm + row) * K + k0 + (c >> 1), sA + (Lb >> 1));
            }
            #pragma unroll
            for (int i = 0; i < 4; ++i) {
                const int Lb  = ((i << 3) + wid) << 10;
                const int L   = Lb + (lane << 4);
                const int row = L >> 7;
                const int c   = (L & 127) ^ ((row & 7) << 4);
                gl_lds16(Wp + (size_t)row * K + k0 + (c >> 1), sB + (Lb >> 1));
            }
            __syncthreads();

            #pragma unroll
            for (int kk = 0; kk < 2; ++kk) {
                const int cb = (kk << 6) + kg16;
                f16x8 af[4], bf[2];
                #pragma unroll
                for (int m = 0; m < 4; ++m) {
                    const int row = m * 16 + lrow;
                    const int c = cb ^ ((row & 7) << 4);
                    af[m] = *reinterpret_cast<const f16x8*>(&sA[row * GBK + (c >> 1)]);
                }
                #pragma unroll
                for (int n = 0; n < 2; ++n) {
                    const int row = wid * 32 + n * 16 + lrow;
                    const int c = cb ^ ((row & 7) << 4);
                    bf[n] = *reinterpret_cast<const f16x8*>(&sB[row * GBK + (c >> 1)]);
                }
                #pragma unroll
                for (int m = 0; m < 4; ++m)
                    #pragma unroll
                    for (int n = 0; n < 2; ++n)
                        acc[m][n] = __builtin_amdgcn_mfma_f32_16x16x32_f16(af[m], bf[n], acc[m][n], 0, 0, 0);
            }
            __syncthreads();
        }
    }

    const int lcol = lane & 15;
    const int rgrp = lane >> 4;
    #pragma unroll
    for (int m = 0; m < 4; ++m) {
        #pragma unroll
        for (int n = 0; n < 2; ++n) {
            const int col = wid * 32 + n * 16 + lcol;
            const float bv = bias[col];
            #pragma unroll
            for (int r = 0; r < 4; ++r) {
                const int row = bm + m * 16 + rgrp * 4 + r;
                if (row >= M) continue;
                float v = acc[m][n][r] + bv;
                if (RELU) v = fmaxf(v, 0.0f);
                if (OUT_F16) ((half_t*)Cout)[(size_t)row * 256 + col] = (half_t)v;
                else         ((float*)Cout)[(size_t)row * 256 + col] = v;
            }
        }
    }
}

static constexpr size_t align256(size_t x) { return (x + 255) & ~(size_t)255; }

extern "C" void kernel_launch(void* const* d_in, const int* in_sizes, int n_in,
                              void* d_out, int out_size, void* d_ws, size_t ws_size,
                              hipStream_t stream)
{
    const float* x    = (const float*)d_in[0];
    const int*  src0  = (const int*)d_in[1];
    const int*  dst0  = (const int*)d_in[2];
    const int*  src1  = (const int*)d_in[3];
    const int*  dst1  = (const int*)d_in[4];
    const int*  src2  = (const int*)d_in[5];
    const int*  dst2  = (const int*)d_in[6];
    const float* Ws0  = (const float*)d_in[7];
    const float* Wn0  = (const float*)d_in[8];
    const float* b0   = (const float*)d_in[9];
    const float* Ws1  = (const float*)d_in[10];
    const float* Wn1  = (const float*)d_in[11];
    const float* b1   = (const float*)d_in[12];
    const float* Ws2  = (const float*)d_in[13];
    const float* Wn2  = (const float*)d_in[14];
    const float* b2   = (const float*)d_in[15];
    const float* W_fc = (const float*)d_in[16];
    const float* b_fc = (const float*)d_in[17];
    float* out = (float*)d_out;

    // ---- workspace layout ----
    char* ws = (char*)d_ws;
    size_t off = 0;
    const size_t cntA_off = off; off = align256(off + (size_t)(N1 + N2 + N3) * 4); // zeroed region
    const size_t ptr0_off = off; off = align256(off + (size_t)(N1 + 1) * 4);
    const size_t ptr1_off = off; off = align256(off + (size_t)(N2 + 1) * 4);
    const size_t ptr2_off = off; off = align256(off + (size_t)(N3 + 1) * 4);
    const size_t cur0_off = off; off = align256(off + (size_t)N1 * 4);
    const size_t cur1_off = off; off = align256(off + (size_t)N2 * 4);
    const size_t cur2_off = off; off = align256(off + (size_t)N3 * 4);
    const size_t es0_off  = off; off = align256(off + (size_t)E0 * 4);
    const size_t es1_off  = off; off = align256(off + (size_t)E1 * 4);
    const size_t es2_off  = off; off = align256(off + (size_t)E2 * 4);
    const size_t xh_off   = off; off = align256(off + (size_t)N0 * D_IN * 2);   // full x fp16
    const size_t mean_off = off; off = align256(off + (size_t)N1 * D_IN * 2);
    const size_t h0_off   = off; off = align256(off + (size_t)N1 * D_H * 2);
    const size_t h1_off   = off; off = align256(off + (size_t)N2 * D_H * 2);
    const size_t h2_off   = off; off = align256(off + (size_t)N3 * D_H * 2);
    const size_t wt0_off  = off; off = align256(off + (size_t)D_IN * D_H * 2);  // WsT0
    const size_t wt1_off  = off; off = align256(off + (size_t)D_IN * D_H * 2);  // WnT0
    const size_t wt2_off  = off; off = align256(off + (size_t)D_H * D_H * 2);   // WsT1
    const size_t wt3_off  = off; off = align256(off + (size_t)D_H * D_H * 2);   // WnT1
    const size_t wt4_off  = off; off = align256(off + (size_t)D_H * D_H * 2);   // WsT2
    const size_t wt5_off  = off; off = align256(off + (size_t)D_H * D_H * 2);   // WnT2
    const size_t wt6_off  = off; off = align256(off + (size_t)D_H * D_H * 2);   // WfcT

    int* cnt0 = (int*)(ws + cntA_off);
    int* cnt1 = cnt0 + N1;
    int* cnt2 = cnt1 + N2;
    int* ptr0 = (int*)(ws + ptr0_off);
    int* ptr1 = (int*)(ws + ptr1_off);
    int* ptr2 = (int*)(ws + ptr2_off);
    int* cur0 = (int*)(ws + cur0_off);
    int* cur1 = (int*)(ws + cur1_off);
    int* cur2 = (int*)(ws + cur2_off);
    int* es0  = (int*)(ws + es0_off);
    int* es1  = (int*)(ws + es1_off);
    int* es2  = (int*)(ws + es2_off);
    half_t* xh   = (half_t*)(ws + xh_off);
    half_t* mean = (half_t*)(ws + mean_off);
    half_t* h0   = (half_t*)(ws + h0_off);
    half_t* h1   = (half_t*)(ws + h1_off);
    half_t* h2   = (half_t*)(ws + h2_off);
    half_t* WsT0 = (half_t*)(ws + wt0_off);
    half_t* WnT0 = (half_t*)(ws + wt1_off);
    half_t* WsT1 = (half_t*)(ws + wt2_off);
    half_t* WnT1 = (half_t*)(ws + wt3_off);
    half_t* WsT2 = (half_t*)(ws + wt4_off);
    half_t* WnT2 = (half_t*)(ws + wt5_off);
    half_t* WfcT = (half_t*)(ws + wt6_off);

    // ---- K1: zero hist, then {xconv-lo | wconv | hist3} ----
    hipMemsetAsync(cnt0, 0, (size_t)(N1 + N2 + N3) * 4, stream);
    front1_kernel<<<XLB + WB + HB, 256, 0, stream>>>(
        x, xh,
        Ws0, Wn0, Ws1, Wn1, Ws2, Wn2, W_fc,
        WsT0, WnT0, WsT1, WnT1, WsT2, WnT2, WfcT,
        dst0, dst1, dst2, cnt0, cnt1, cnt2);
    // ---- K2: scan ----
    scan3_kernel<<<3, 1024, 0, stream>>>(cnt0, ptr0, cur0, cnt1, ptr1, cur1, cnt2, ptr2, cur2);
    // ---- K3: fill ----
    {
        const int tot = E0 + E1 + E2;
        fill3_kernel<<<(tot + 255) / 256, 256, 0, stream>>>(
            src0, dst0, src1, dst1, src2, dst2, cur0, cur1, cur2, es0, es1, es2);
    }
    // ---- K4: {xconv-hi || gather-lo}, interleaved ----
    front2_kernel<<<XLB + 3125, 256, 0, stream>>>(x, xh, es0, ptr0, mean);
    // ---- K5: gather-hi ----
    gather_hi_kernel<<<3125, 256, 0, stream>>>(xh, es0, ptr0, mean);

    // ---- layer-0 GEMM ----
    mfma_gemm<true, true, true><<<(N1 + GBM - 1) / GBM, 512, 0, stream>>>(
        xh, mean, WsT0, WnT0, b0, h0, N1, D_IN);
    // ---- layer 1 ----
    {
        constexpr int NPB = 256 / (D_H / 8);    // 8
        csr_mean_f16<D_H><<<(N2 + NPB - 1) / NPB, 256, 0, stream>>>(h0, es1, ptr1, mean, N2);
        mfma_gemm<true, true, true><<<(N2 + GBM - 1) / GBM, 512, 0, stream>>>(
            h0, mean, WsT1, WnT1, b1, h1, N2, D_H);
    }
    // ---- layer 2 (no relu) ----
    {
        constexpr int NPB = 256 / (D_H / 8);
        csr_mean_f16<D_H><<<(N3 + NPB - 1) / NPB, 256, 0, stream>>>(h1, es2, ptr2, mean, N3);
        mfma_gemm<true, false, true><<<(N3 + GBM - 1) / GBM, 512, 0, stream>>>(
            h1, mean, WsT2, WnT2, b2, h2, N3, D_H);
    }
    // ---- final FC (fp32 out) ----
    mfma_gemm<false, false, false><<<(N3 + GBM - 1) / GBM, 512, 0, stream>>>(
        h2, nullptr, WfcT, nullptr, b_fc, out, N3, D_H);
}

// Round 11
// 288.416 us; speedup vs baseline: 1.0122x; 1.0122x over previous
//
#include <hip/hip_runtime.h>
#include <hip/hip_bf16.h>
#include <cstddef>
#include <cstdint>

// Problem constants
#define N0 100000
#define N1 25000
#define N2 6250
#define N3 1600
#define DEG 16
#define D_IN 512
#define D_H 256

#define E0 (N1*DEG)   // 400000
#define E1 (N2*DEG)   // 100000
#define E2 (N3*DEG)   // 25600

typedef _Float16 half_t;
typedef __attribute__((ext_vector_type(8))) _Float16 f16x8;
typedef __attribute__((ext_vector_type(4))) float f32x4;

// block-range partition of the fused conversion kernel
#define XB 25000                        // xconv blocks: N0*512/8/256
#define WB 2304                         // wconv blocks: 589824/256
#define HB (((E0+E1+E2) + 255) / 256)   // hist blocks:  2054

// ---------------------------------------------------------------------------
// async global -> LDS, 16 bytes per lane. LDS dest = wave-uniform base +
// lane*16 (linear); global src per-lane (pre-swizzled).
// ---------------------------------------------------------------------------
__device__ __forceinline__ void gl_lds16(const void* g, void* l)
{
    __builtin_amdgcn_global_load_lds(
        (const __attribute__((address_space(1))) void*)g,
        (__attribute__((address_space(3))) void*)l,
        16, 0, 0);
}

// ---------------------------------------------------------------------------
// Fused: xconv (fp32 x -> fp16 xh) | wconv (7 weights transpose+fp16) | hist3
// ---------------------------------------------------------------------------
__global__ __launch_bounds__(256)
void mega_conv_kernel(const float* __restrict__ x, half_t* __restrict__ xh,
                      const float* s0, const float* s1, const float* s2, const float* s3,
                      const float* s4, const float* s5, const float* s6,
                      half_t* t0, half_t* t1, half_t* t2, half_t* t3,
                      half_t* t4, half_t* t5, half_t* t6,
                      const int* __restrict__ d0, const int* __restrict__ d1,
                      const int* __restrict__ d2,
                      int* __restrict__ c0, int* __restrict__ c1, int* __restrict__ c2)
{
    const int bid = blockIdx.x;
    if (bid < XB) {
        const int id = bid * 256 + threadIdx.x;          // < 6.4M
        const float4* p = reinterpret_cast<const float4*>(x) + (size_t)id * 2;
        const float4 a = p[0], b = p[1];
        f16x8 o;
        o[0] = (half_t)a.x; o[1] = (half_t)a.y; o[2] = (half_t)a.z; o[3] = (half_t)a.w;
        o[4] = (half_t)b.x; o[5] = (half_t)b.y; o[6] = (half_t)b.z; o[7] = (half_t)b.w;
        *(reinterpret_cast<f16x8*>(xh) + id) = o;
    } else if (bid < XB + WB) {
        const int id = (bid - XB) * 256 + threadIdx.x;
        const float* src; half_t* dst; int kb; int e;
        if (id < 131072)      { src = s0; dst = t0; kb = 9; e = id; }
        else if (id < 262144) { src = s1; dst = t1; kb = 9; e = id - 131072; }
        else if (id < 327680) { src = s2; dst = t2; kb = 8; e = id - 262144; }
        else if (id < 393216) { src = s3; dst = t3; kb = 8; e = id - 327680; }
        else if (id < 458752) { src = s4; dst = t4; kb = 8; e = id - 393216; }
        else if (id < 524288) { src = s5; dst = t5; kb = 8; e = id - 458752; }
        else if (id < 589824) { src = s6; dst = t6; kb = 8; e = id - 524288; }
        else return;
        const int K = 1 << kb;
        const int nn = e >> kb, k = e & (K - 1);
        dst[((size_t)nn << kb) + k] = (half_t)src[(size_t)k * 256 + nn];
    } else {
        const int i = (bid - XB - WB) * 256 + threadIdx.x;
        if (i < E0)                atomicAdd(&c0[d0[i]], 1);
        else if (i < E0 + E1)      atomicAdd(&c1[d1[i - E0]], 1);
        else if (i < E0 + E1 + E2) atomicAdd(&c2[d2[i - E0 - E1]], 1);
    }
}

// ---------------------------------------------------------------------------
// fill3: scatter src values into dst-ordered buckets
// ---------------------------------------------------------------------------
__global__ void fill3_kernel(const int* __restrict__ s0, const int* __restrict__ d0,
                             const int* __restrict__ s1, const int* __restrict__ d1,
                             const int* __restrict__ s2, const int* __restrict__ d2,
                             int* __restrict__ u0, int* __restrict__ u1, int* __restrict__ u2,
                             int* __restrict__ e0, int* __restrict__ e1, int* __restrict__ e2)
{
    const int i = blockIdx.x * 256 + threadIdx.x;
    if (i < E0) {
        const int p = atomicAdd(&u0[d0[i]], 1); e0[p] = s0[i];
    } else if (i < E0 + E1) {
        const int j = i - E0;
        const int p = atomicAdd(&u1[d1[j]], 1); e1[p] = s1[j];
    } else if (i < E0 + E1 + E2) {
        const int j = i - E0 - E1;
        const int p = atomicAdd(&u2[d2[j]], 1); e2[p] = s2[j];
    }
}

// 3-phase block scan; block b handles layer b. Writes ptr[0..n] and cursor[0..n).
__global__ __launch_bounds__(1024)
void scan3_kernel(const int* __restrict__ c0, int* __restrict__ p0, int* __restrict__ u0,
                  const int* __restrict__ c1, int* __restrict__ p1, int* __restrict__ u1,
                  const int* __restrict__ c2, int* __restrict__ p2, int* __restrict__ u2)
{
    const int b = blockIdx.x;
    const int* cnt = (b == 0) ? c0 : (b == 1) ? c1 : c2;
    int* ptr = (b == 0) ? p0 : (b == 1) ? p1 : p2;
    int* cur = (b == 0) ? u0 : (b == 1) ? u1 : u2;
    const int n = (b == 0) ? N1 : (b == 1) ? N2 : N3;

    const int t = threadIdx.x;
    const int chunk = (n + 1023) >> 10;
    const int beg = t * chunk;
    const int end = min(n, beg + chunk);

    int sum = 0;
    for (int i = beg; i < end; ++i) sum += cnt[i];

    const int lane = t & 63, wid = t >> 6;
    int inc = sum;
    #pragma unroll
    for (int d = 1; d < 64; d <<= 1) {
        int u = __shfl_up(inc, d, 64);
        if (lane >= d) inc += u;
    }
    __shared__ int wtot[16];
    __shared__ int total_s;
    if (lane == 63) wtot[wid] = inc;
    __syncthreads();
    if (wid == 0) {
        int w = (lane < 16) ? wtot[lane] : 0;
        int ws = w;
        #pragma unroll
        for (int d = 1; d < 16; d <<= 1) {
            int u = __shfl_up(ws, d, 64);
            if (lane >= d) ws += u;
        }
        if (lane < 16) wtot[lane] = ws - w;   // exclusive wave offset
        if (lane == 15) total_s = ws;         // block total
    }
    __syncthreads();
    int run = (inc - sum) + wtot[wid];
    for (int i = beg; i < end; ++i) {
        ptr[i] = run; cur[i] = run;
        run += cnt[i];
    }
    if (t == 0) ptr[n] = total_s;
}

// ---------------------------------------------------------------------------
// CSR gather-mean, fp16 in, fp32 accumulate, fp16 out.
// TPN = K/8 lanes per node; indices lane-loaded + shfl broadcast; x8 unroll.
// ---------------------------------------------------------------------------
template<int K>
__global__ __launch_bounds__(256)
void csr_mean_f16(const half_t* __restrict__ h, const int* __restrict__ esrc,
                  const int* __restrict__ ptr, half_t* __restrict__ mean, int n)
{
    constexpr int TPN = K / 8;
    constexpr int NPB = 256 / TPN;
    const int node = blockIdx.x * NPB + threadIdx.x / TPN;
    const int lane = threadIdx.x % TPN;
    if (node >= n) return;
    const int beg = ptr[node], end = ptr[node + 1];
    float acc[8] = {};
    for (int base = beg; base < end; base += TPN) {
        const int rem = end - base;
        const int cnt = (rem < TPN) ? rem : TPN;
        const int myidx = (lane < cnt) ? esrc[base + lane] : 0;
        int j = 0;
        for (; j + 7 < cnt; j += 8) {
            int a[8];
            #pragma unroll
            for (int u = 0; u < 8; ++u) a[u] = __shfl(myidx, j + u, TPN);
            f16x8 v[8];
            #pragma unroll
            for (int u = 0; u < 8; ++u)
                v[u] = *reinterpret_cast<const f16x8*>(h + (size_t)a[u] * K + (size_t)lane * 8);
            #pragma unroll
            for (int u = 0; u < 8; ++u)
                #pragma unroll
                for (int i = 0; i < 8; ++i) acc[i] += (float)v[u][i];
        }
        for (; j < cnt; ++j) {
            const int a0 = __shfl(myidx, j, TPN);
            const f16x8 v0 = *reinterpret_cast<const f16x8*>(h + (size_t)a0 * K + (size_t)lane * 8);
            #pragma unroll
            for (int i = 0; i < 8; ++i) acc[i] += (float)v0[i];
        }
    }
    const float r = 1.0f / fmaxf((float)(end - beg), 1.0f);
    f16x8 o;
    #pragma unroll
    for (int i = 0; i < 8; ++i) o[i] = (half_t)(acc[i] * r);
    *reinterpret_cast<f16x8*>(mean + (size_t)node * K + (size_t)lane * 8) = o;
}

// ---------------------------------------------------------------------------
// MFMA GEMM: C[M x 256] = A @ WsT^T (+ Mean @ WnT^T) + bias, optional ReLU.
// A, Mean: fp16 [M][K]. WsT/WnT: fp16 [256][K] (pre-transposed).
// Tile BM=64 x BN=256 (full width), BK=64 halfs (128 B rows).
// 512 threads = 8 waves; wave w owns cols [32w,32w+32): acc 4x2 fragments.
// Staging: global_load_lds width 16 into XOR-swizzled linear LDS
//   LDS[row][c] = G[row][c ^ ((row&7)<<4)] (byte cols); reads use same XOR.
// ---------------------------------------------------------------------------
#define GBM 64
#define GBK 64

template<bool HAS_MEAN, bool RELU, bool OUT_F16>
__global__ __launch_bounds__(512)
void mfma_gemm(const half_t* __restrict__ A,
               const half_t* __restrict__ Mn,
               const half_t* __restrict__ WsT,
               const half_t* __restrict__ WnT,
               const float* __restrict__ bias,
               void* __restrict__ Cout,
               int M, int K)
{
    __shared__ half_t sA[GBM * GBK];    // 8 KB
    __shared__ half_t sB[256 * GBK];    // 32 KB

    const int tid  = threadIdx.x;
    const int wid  = tid >> 6;          // 0..7
    const int lane = tid & 63;
    const int bm   = blockIdx.x * GBM;

    const int lrow = lane & 15;
    const int kg16 = (lane >> 4) << 4;  // k-slice byte offset: 0,16,32,48

    f32x4 acc[4][2] = {};

    const int npass = HAS_MEAN ? 2 : 1;
    for (int pass = 0; pass < npass; ++pass) {
        const half_t* __restrict__ Ap = (HAS_MEAN && pass) ? Mn : A;
        const half_t* __restrict__ Wp = (HAS_MEAN && pass) ? WnT : WsT;

        for (int k0 = 0; k0 < K; k0 += GBK) {
            // ---- stage A: 8 KB = 8 waves x 1 chunk x 1 KB ----
            {
                const int Lb  = wid << 10;                    // wave-uniform
                const int L   = Lb + (lane << 4);
                const int row = L >> 7;
                const int c   = (L & 127) ^ ((row & 7) << 4); // pre-swizzled src col
                gl_lds16(Ap + (size_t)(bm + row) * K + k0 + (c >> 1), sA + (Lb >> 1));
            }
            // ---- stage B: 32 KB = 8 waves x 4 chunks x 1 KB ----
            #pragma unroll
            for (int i = 0; i < 4; ++i) {
                const int Lb  = ((i << 3) + wid) << 10;
                const int L   = Lb + (lane << 4);
                const int row = L >> 7;
                const int c   = (L & 127) ^ ((row & 7) << 4);
                gl_lds16(Wp + (size_t)row * K + k0 + (c >> 1), sB + (Lb >> 1));
            }
            __syncthreads();   // drains vmcnt before use

            #pragma unroll
            for (int kk = 0; kk < 2; ++kk) {
                const int cb = (kk << 6) + kg16;
                f16x8 af[4], bf[2];
                #pragma unroll
                for (int m = 0; m < 4; ++m) {
                    const int row = m * 16 + lrow;
                    const int c = cb ^ ((row & 7) << 4);
                    af[m] = *reinterpret_cast<const f16x8*>(&sA[row * GBK + (c >> 1)]);
                }
                #pragma unroll
                for (int n = 0; n < 2; ++n) {
                    const int row = wid * 32 + n * 16 + lrow;
                    const int c = cb ^ ((row & 7) << 4);
                    bf[n] = *reinterpret_cast<const f16x8*>(&sB[row * GBK + (c >> 1)]);
                }
                #pragma unroll
                for (int m = 0; m < 4; ++m)
                    #pragma unroll
                    for (int n = 0; n < 2; ++n)
                        acc[m][n] = __builtin_amdgcn_mfma_f32_16x16x32_f16(af[m], bf[n], acc[m][n], 0, 0, 0);
            }
            __syncthreads();   // before next-step overwrite
        }
    }

    // epilogue: D row=(lane>>4)*4+r, col=lane&15 within each 16x16 fragment
    const int lcol = lane & 15;
    const int rgrp = lane >> 4;
    #pragma unroll
    for (int m = 0; m < 4; ++m) {
        #pragma unroll
        for (int n = 0; n < 2; ++n) {
            const int col = wid * 32 + n * 16 + lcol;
            const float bv = bias[col];
            #pragma unroll
            for (int r = 0; r < 4; ++r) {
                const int row = bm + m * 16 + rgrp * 4 + r;
                if (row >= M) continue;
                float v = acc[m][n][r] + bv;
                if (RELU) v = fmaxf(v, 0.0f);
                if (OUT_F16) ((half_t*)Cout)[(size_t)row * 256 + col] = (half_t)v;
                else         ((float*)Cout)[(size_t)row * 256 + col] = v;
            }
        }
    }
}

static constexpr size_t align256(size_t x) { return (x + 255) & ~(size_t)255; }

extern "C" void kernel_launch(void* const* d_in, const int* in_sizes, int n_in,
                              void* d_out, int out_size, void* d_ws, size_t ws_size,
                              hipStream_t stream)
{
    const float* x    = (const float*)d_in[0];
    const int*  src0  = (const int*)d_in[1];
    const int*  dst0  = (const int*)d_in[2];
    const int*  src1  = (const int*)d_in[3];
    const int*  dst1  = (const int*)d_in[4];
    const int*  src2  = (const int*)d_in[5];
    const int*  dst2  = (const int*)d_in[6];
    const float* Ws0  = (const float*)d_in[7];
    const float* Wn0  = (const float*)d_in[8];
    const float* b0   = (const float*)d_in[9];
    const float* Ws1  = (const float*)d_in[10];
    const float* Wn1  = (const float*)d_in[11];
    const float* b1   = (const float*)d_in[12];
    const float* Ws2  = (const float*)d_in[13];
    const float* Wn2  = (const float*)d_in[14];
    const float* b2   = (const float*)d_in[15];
    const float* W_fc = (const float*)d_in[16];
    const float* b_fc = (const float*)d_in[17];
    float* out = (float*)d_out;

    // ---- workspace layout ----
    char* ws = (char*)d_ws;
    size_t off = 0;
    const size_t cntA_off = off; off = align256(off + (size_t)(N1 + N2 + N3) * 4); // zeroed region
    const size_t ptr0_off = off; off = align256(off + (size_t)(N1 + 1) * 4);
    const size_t ptr1_off = off; off = align256(off + (size_t)(N2 + 1) * 4);
    const size_t ptr2_off = off; off = align256(off + (size_t)(N3 + 1) * 4);
    const size_t cur0_off = off; off = align256(off + (size_t)N1 * 4);
    const size_t cur1_off = off; off = align256(off + (size_t)N2 * 4);
    const size_t cur2_off = off; off = align256(off + (size_t)N3 * 4);
    const size_t es0_off  = off; off = align256(off + (size_t)E0 * 4);
    const size_t es1_off  = off; off = align256(off + (size_t)E1 * 4);
    const size_t es2_off  = off; off = align256(off + (size_t)E2 * 4);
    const size_t xh_off   = off; off = align256(off + (size_t)N0 * D_IN * 2);   // full x fp16
    const size_t mean_off = off; off = align256(off + (size_t)N1 * D_IN * 2);
    const size_t h0_off   = off; off = align256(off + (size_t)N1 * D_H * 2);
    const size_t h1_off   = off; off = align256(off + (size_t)N2 * D_H * 2);
    const size_t h2_off   = off; off = align256(off + (size_t)N3 * D_H * 2);
    const size_t wt0_off  = off; off = align256(off + (size_t)D_IN * D_H * 2);  // WsT0
    const size_t wt1_off  = off; off = align256(off + (size_t)D_IN * D_H * 2);  // WnT0
    const size_t wt2_off  = off; off = align256(off + (size_t)D_H * D_H * 2);   // WsT1
    const size_t wt3_off  = off; off = align256(off + (size_t)D_H * D_H * 2);   // WnT1
    const size_t wt4_off  = off; off = align256(off + (size_t)D_H * D_H * 2);   // WsT2
    const size_t wt5_off  = off; off = align256(off + (size_t)D_H * D_H * 2);   // WnT2
    const size_t wt6_off  = off; off = align256(off + (size_t)D_H * D_H * 2);   // WfcT

    int* cnt0 = (int*)(ws + cntA_off);
    int* cnt1 = cnt0 + N1;
    int* cnt2 = cnt1 + N2;
    int* ptr0 = (int*)(ws + ptr0_off);
    int* ptr1 = (int*)(ws + ptr1_off);
    int* ptr2 = (int*)(ws + ptr2_off);
    int* cur0 = (int*)(ws + cur0_off);
    int* cur1 = (int*)(ws + cur1_off);
    int* cur2 = (int*)(ws + cur2_off);
    int* es0  = (int*)(ws + es0_off);
    int* es1  = (int*)(ws + es1_off);
    int* es2  = (int*)(ws + es2_off);
    half_t* xh   = (half_t*)(ws + xh_off);
    half_t* mean = (half_t*)(ws + mean_off);
    half_t* h0   = (half_t*)(ws + h0_off);
    half_t* h1   = (half_t*)(ws + h1_off);
    half_t* h2   = (half_t*)(ws + h2_off);
    half_t* WsT0 = (half_t*)(ws + wt0_off);
    half_t* WnT0 = (half_t*)(ws + wt1_off);
    half_t* WsT1 = (half_t*)(ws + wt2_off);
    half_t* WnT1 = (half_t*)(ws + wt3_off);
    half_t* WsT2 = (half_t*)(ws + wt4_off);
    half_t* WnT2 = (half_t*)(ws + wt5_off);
    half_t* WfcT = (half_t*)(ws + wt6_off);

    // ---- zero histograms, then fused conv+hist, scan, fill ----
    hipMemsetAsync(cnt0, 0, (size_t)(N1 + N2 + N3) * 4, stream);
    mega_conv_kernel<<<XB + WB + HB, 256, 0, stream>>>(
        x, xh,
        Ws0, Wn0, Ws1, Wn1, Ws2, Wn2, W_fc,
        WsT0, WnT0, WsT1, WnT1, WsT2, WnT2, WfcT,
        dst0, dst1, dst2, cnt0, cnt1, cnt2);
    scan3_kernel<<<3, 1024, 0, stream>>>(cnt0, ptr0, cur0, cnt1, ptr1, cur1, cnt2, ptr2, cur2);
    {
        const int tot = E0 + E1 + E2;
        fill3_kernel<<<(tot + 255) / 256, 256, 0, stream>>>(
            src0, dst0, src1, dst1, src2, dst2, cur0, cur1, cur2, es0, es1, es2);
    }

    // ---- layer 0 ----
    {
        constexpr int NPB = 256 / (D_IN / 8);   // 4 nodes / block
        csr_mean_f16<D_IN><<<(N1 + NPB - 1) / NPB, 256, 0, stream>>>(xh, es0, ptr0, mean, N1);
        mfma_gemm<true, true, true><<<(N1 + GBM - 1) / GBM, 512, 0, stream>>>(
            xh, mean, WsT0, WnT0, b0, h0, N1, D_IN);
    }
    // ---- layer 1 ----
    {
        constexpr int NPB = 256 / (D_H / 8);    // 8
        csr_mean_f16<D_H><<<(N2 + NPB - 1) / NPB, 256, 0, stream>>>(h0, es1, ptr1, mean, N2);
        mfma_gemm<true, true, true><<<(N2 + GBM - 1) / GBM, 512, 0, stream>>>(
            h0, mean, WsT1, WnT1, b1, h1, N2, D_H);
    }
    // ---- layer 2 (no relu) ----
    {
        constexpr int NPB = 256 / (D_H / 8);
        csr_mean_f16<D_H><<<(N3 + NPB - 1) / NPB, 256, 0, stream>>>(h1, es2, ptr2, mean, N3);
        mfma_gemm<true, false, true><<<(N3 + GBM - 1) / GBM, 512, 0, stream>>>(
            h1, mean, WsT2, WnT2, b2, h2, N3, D_H);
    }
    // ---- final FC (fp32 out) ----
    mfma_gemm<false, false, false><<<(N3 + GBM - 1) / GBM, 512, 0, stream>>>(
        h2, nullptr, WfcT, nullptr, b_fc, out, N3, D_H);
}